// Round 9
// baseline (6363.708 us; speedup 1.0000x reference)
//
#include <hip/hip_runtime.h>

typedef _Float16 f16x8 __attribute__((ext_vector_type(8)));
typedef float f32x4 __attribute__((ext_vector_type(4)));

#define LOG2E 1.44269504088896340736f
#define MELEM 16          // batch elems per block (1 M-tile of 16)
#define HS 72             // f16 stride of h LDS rows (16B-aligned, bank-spread)
#define INV2K 4.8828125e-4f   // 2^-11
#define SC2K  2048.0f         // 2^11

__device__ __forceinline__ float fast_sigmoid(float x) {
    float t = __builtin_amdgcn_exp2f(-x * LOG2E);
    return __builtin_amdgcn_rcpf(1.f + t);
}
__device__ __forceinline__ float fast_tanh(float x) {
    float t = __builtin_amdgcn_exp2f(x * (2.f * LOG2E));
    return 1.f - 2.f * __builtin_amdgcn_rcpf(1.f + t);
}
__device__ __forceinline__ float bpermf(int sa, float v) {
    return __builtin_bit_cast(float,
        __builtin_amdgcn_ds_bpermute(sa, __builtin_bit_cast(int, v)));
}

__global__ __launch_bounds__(256, 4)
void gru_mfma_kernel(const float* __restrict__ z0,
                     const float* __restrict__ dtp,
                     const int* __restrict__ stepsp,
                     const float* __restrict__ Wih,
                     const float* __restrict__ Whh,
                     const float* __restrict__ bih,
                     const float* __restrict__ bhh,
                     const float* __restrict__ Whead,
                     const float* __restrict__ bhead,
                     float* __restrict__ out)
{
    // ping-pong fp16 2-way split of h: [pp][part hi/lo][elem*HS + unit]  (9216 B)
    __shared__ _Float16 hbuf[2][2][MELEM*HS];

    const int tid = threadIdx.x;
    const int w   = tid >> 6;       // wave 0..3 -> unit range [16w,16w+16)
    const int l   = tid & 63;
    const int c16 = l & 15;
    const int g   = l >> 4;         // 0..3
    const int unit = 16*w + c16;

    const float dtv = dtp[0];
    const int nsteps = stepsp[0];
    const size_t T3 = (size_t)(nsteps + 1) * 3;
    const long blk = blockIdx.x;

    // ---- B-fragments of W_hh: fp16 hi + 2^11-scaled lo, ALL in registers ----
    f16x8 WBh[3][2], WBl[3][2];
    #pragma unroll
    for (int gate = 0; gate < 3; ++gate) {
        const float* row = Whh + (size_t)(gate*64 + unit) * 64;
        #pragma unroll
        for (int kk = 0; kk < 2; ++kk) {
            const float* p = row + 32*kk + 8*g;
            f16x8 bh_, bl_;
            #pragma unroll
            for (int j = 0; j < 8; ++j) {
                float x = p[j];
                _Float16 hi = (_Float16)x;
                bh_[j] = hi;
                bl_[j] = (_Float16)((x - (float)hi) * SC2K);
            }
            WBh[gate][kk] = bh_;
            WBl[gate][kk] = bl_;
        }
    }
    // ---- head B-fragments in regs (cols >= 3 zero) ----
    f16x8 HBh[2], HBl[2];
    {
        f16x8 zf = {0,0,0,0,0,0,0,0};
        HBh[0]=zf; HBh[1]=zf; HBl[0]=zf; HBl[1]=zf;
        if (c16 < 3) {
            #pragma unroll
            for (int kk = 0; kk < 2; ++kk) {
                const float* p = Whead + (size_t)c16*64 + 32*kk + 8*g;
                f16x8 bh_, bl_;
                #pragma unroll
                for (int j = 0; j < 8; ++j) {
                    float x = p[j];
                    _Float16 hi = (_Float16)x;
                    bh_[j] = hi;
                    bl_[j] = (_Float16)((x - (float)hi) * SC2K);
                }
                HBh[kk] = bh_; HBl[kk] = bl_;
            }
        }
    }

    // ---- per-lane scalar weights / biases ----
    const float wir0 = Wih[(0*64+unit)*3+0], wir1 = Wih[(0*64+unit)*3+1], wir2 = Wih[(0*64+unit)*3+2];
    const float wiu0 = Wih[(1*64+unit)*3+0], wiu1 = Wih[(1*64+unit)*3+1], wiu2 = Wih[(1*64+unit)*3+2];
    const float win0 = Wih[(2*64+unit)*3+0], win1 = Wih[(2*64+unit)*3+1], win2 = Wih[(2*64+unit)*3+2];
    const float br   = bih[0*64+unit] + bhh[0*64+unit];
    const float bu   = bih[1*64+unit] + bhh[1*64+unit];
    const float bin_ = bih[2*64+unit];
    const float bhn  = bhh[2*64+unit];
    float bhc = 0.f;
    if (c16 < 3) bhc = bhead[c16];

    // ---- z in registers: lane holds rows 4g+r (r=0..3) of the 16-elem tile ----
    float zreg[4][3];
    #pragma unroll
    for (int r = 0; r < 4; ++r)
        #pragma unroll
        for (int c = 0; c < 3; ++c)
            zreg[r][c] = z0[(size_t)(blk*MELEM + 4*g + r)*3 + c];

    // ---- out cursor (designated lanes: wave 0, c16<3) ----
    float* o0 = out;
    if (w == 0 && c16 < 3)
        o0 = out + (size_t)(blk*MELEM + 4*g)*T3 + c16;
    // t=0 row (static zreg indices via unrolled predication)
    #pragma unroll
    for (int c = 0; c < 3; ++c)
        if (w == 0 && c16 == c) {
            #pragma unroll
            for (int r = 0; r < 4; ++r) o0[(size_t)r*T3] = zreg[r][c];
        }
    o0 += 3;   // -> t=1 (garbage-but-unused on non-designated lanes)

    // hoisted bpermute byte-addresses
    const int sa0 = (l & 48) << 2;
    const int sa1 = sa0 + 4;
    const int sa2 = sa0 + 8;

    // step-invariant LDS element offset for A-fragments (row = c16)
    const int adA0 = c16*HS + 8*g;

    // ---- zero h buffer 0 (h_0 = 0) ----
    {
        uint* hz = (uint*)&hbuf[0][0][0];
        for (int i = tid; i < MELEM*HS; i += 256) hz[i] = 0u;
    }

    float hC[4] = {0.f,0.f,0.f,0.f};

    __syncthreads();

#define GATE(GT, GR) do {                                                        \
    f32x4 a1 = {0.f,0.f,0.f,0.f}, a2 = {0.f,0.f,0.f,0.f};                        \
    a1 = __builtin_amdgcn_mfma_f32_16x16x32_f16(FAh0, WBh[GT][0], a1, 0,0,0);    \
    a2 = __builtin_amdgcn_mfma_f32_16x16x32_f16(FAh0, WBl[GT][0], a2, 0,0,0);    \
    a2 = __builtin_amdgcn_mfma_f32_16x16x32_f16(FAl0, WBh[GT][0], a2, 0,0,0);    \
    a1 = __builtin_amdgcn_mfma_f32_16x16x32_f16(FAh1, WBh[GT][1], a1, 0,0,0);    \
    a2 = __builtin_amdgcn_mfma_f32_16x16x32_f16(FAh1, WBl[GT][1], a2, 0,0,0);    \
    a2 = __builtin_amdgcn_mfma_f32_16x16x32_f16(FAl1, WBh[GT][1], a2, 0,0,0);    \
    GR = a1;                                                                     \
    _Pragma("unroll")                                                            \
    for (int rr = 0; rr < 4; ++rr) GR[rr] = __builtin_fmaf(INV2K, a2[rr], GR[rr]); \
} while (0)

#define STEP(P, DOZ) do {                                                        \
    f16x8 FAh0 = *(const f16x8*)&hbuf[P][0][adA0];                               \
    f16x8 FAh1 = *(const f16x8*)&hbuf[P][0][adA0 + 32];                          \
    f16x8 FAl0 = *(const f16x8*)&hbuf[P][1][adA0];                               \
    f16x8 FAl1 = *(const f16x8*)&hbuf[P][1][adA0 + 32];                          \
    if (DOZ) {                                                                   \
        f32x4 ha = {0.f,0.f,0.f,0.f}, hb = {0.f,0.f,0.f,0.f};                    \
        ha = __builtin_amdgcn_mfma_f32_16x16x32_f16(FAh0, HBh[0], ha, 0,0,0);    \
        ha = __builtin_amdgcn_mfma_f32_16x16x32_f16(FAh1, HBh[1], ha, 0,0,0);    \
        hb = __builtin_amdgcn_mfma_f32_16x16x32_f16(FAh0, HBl[0], hb, 0,0,0);    \
        hb = __builtin_amdgcn_mfma_f32_16x16x32_f16(FAl0, HBh[0], hb, 0,0,0);    \
        hb = __builtin_amdgcn_mfma_f32_16x16x32_f16(FAh1, HBl[1], hb, 0,0,0);    \
        hb = __builtin_amdgcn_mfma_f32_16x16x32_f16(FAl1, HBh[1], hb, 0,0,0);    \
        _Pragma("unroll")                                                        \
        for (int r = 0; r < 4; ++r) {                                            \
            float fv = ha[r] + INV2K*hb[r] + bhc;                                \
            zreg[r][0] = __builtin_fmaf(dtv, bpermf(sa0, fv), zreg[r][0]);       \
            zreg[r][1] = __builtin_fmaf(dtv, bpermf(sa1, fv), zreg[r][1]);       \
            zreg[r][2] = __builtin_fmaf(dtv, bpermf(sa2, fv), zreg[r][2]);       \
        }                                                                        \
        _Pragma("unroll")                                                        \
        for (int c = 0; c < 3; ++c)                                              \
            if (w == 0 && c16 == c) {                                            \
                _Pragma("unroll")                                                \
                for (int r = 0; r < 4; ++r) o0[(size_t)r*T3] = zreg[r][c];       \
            }                                                                    \
        o0 += 3;                                                                 \
    }                                                                            \
    f32x4 gr0, gr1, gr2;                                                         \
    GATE(0, gr0); GATE(1, gr1); GATE(2, gr2);                                    \
    _Pragma("unroll")                                                            \
    for (int r = 0; r < 4; ++r) {                                                \
        float z0v = zreg[r][0], z1v = zreg[r][1], z2v = zreg[r][2];              \
        float ar  = gr0[r] + br  + (wir0*z0v + wir1*z1v + wir2*z2v);             \
        float au  = gr1[r] + bu  + (wiu0*z0v + wiu1*z1v + wiu2*z2v);             \
        float anh = gr2[r] + bhn;                                                \
        float ain = bin_ + (win0*z0v + win1*z1v + win2*z2v);                     \
        float rg = fast_sigmoid(ar);                                             \
        float ug = fast_sigmoid(au);                                             \
        float ng = fast_tanh(ain + rg*anh);                                      \
        float hn = ng + ug*(hC[r] - ng);                                         \
        hC[r] = hn;                                                              \
        _Float16 hi = (_Float16)hn;                                              \
        _Float16 lo = (_Float16)((hn - (float)hi) * SC2K);                       \
        hbuf[(P)^1][0][(4*g+r)*HS + unit] = hi;                                  \
        hbuf[(P)^1][1][(4*g+r)*HS + unit] = lo;                                  \
    }                                                                            \
    __syncthreads();                                                             \
} while (0)

#define EPI(P) do {                                                              \
    f16x8 FAh0 = *(const f16x8*)&hbuf[P][0][adA0];                               \
    f16x8 FAh1 = *(const f16x8*)&hbuf[P][0][adA0 + 32];                          \
    f16x8 FAl0 = *(const f16x8*)&hbuf[P][1][adA0];                               \
    f16x8 FAl1 = *(const f16x8*)&hbuf[P][1][adA0 + 32];                          \
    f32x4 ha = {0.f,0.f,0.f,0.f}, hb = {0.f,0.f,0.f,0.f};                        \
    ha = __builtin_amdgcn_mfma_f32_16x16x32_f16(FAh0, HBh[0], ha, 0,0,0);        \
    ha = __builtin_amdgcn_mfma_f32_16x16x32_f16(FAh1, HBh[1], ha, 0,0,0);        \
    hb = __builtin_amdgcn_mfma_f32_16x16x32_f16(FAh0, HBl[0], hb, 0,0,0);        \
    hb = __builtin_amdgcn_mfma_f32_16x16x32_f16(FAl0, HBh[0], hb, 0,0,0);        \
    hb = __builtin_amdgcn_mfma_f32_16x16x32_f16(FAh1, HBl[1], hb, 0,0,0);        \
    hb = __builtin_amdgcn_mfma_f32_16x16x32_f16(FAl1, HBh[1], hb, 0,0,0);        \
    _Pragma("unroll")                                                            \
    for (int r = 0; r < 4; ++r) {                                                \
        float fv = ha[r] + INV2K*hb[r] + bhc;                                    \
        zreg[r][0] = __builtin_fmaf(dtv, bpermf(sa0, fv), zreg[r][0]);           \
        zreg[r][1] = __builtin_fmaf(dtv, bpermf(sa1, fv), zreg[r][1]);           \
        zreg[r][2] = __builtin_fmaf(dtv, bpermf(sa2, fv), zreg[r][2]);           \
    }                                                                            \
    _Pragma("unroll")                                                            \
    for (int c = 0; c < 3; ++c)                                                  \
        if (w == 0 && c16 == c) {                                                \
            _Pragma("unroll")                                                    \
            for (int r = 0; r < 4; ++r) o0[(size_t)r*T3] = zreg[r][c];           \
        }                                                                        \
} while (0)

    // ---- main loop: peel t=0, then pairs (compile-time ping-pong) ----
    STEP(0, false);
    int t = 1;
    for (; t + 1 < nsteps; t += 2) {
        STEP(1, true);
        STEP(0, true);
    }
    if (t < nsteps) { STEP(1, true); ++t; }

    // ---- epilogue: z(nsteps) from head over h(nsteps) ----
    if (nsteps & 1) EPI(1); else EPI(0);

#undef STEP
#undef GATE
#undef EPI
}

extern "C" void kernel_launch(void* const* d_in, const int* in_sizes, int n_in,
                              void* d_out, int out_size, void* d_ws, size_t ws_size,
                              hipStream_t stream) {
    const float* z0    = (const float*)d_in[0];
    const float* dtp   = (const float*)d_in[1];
    const int*   steps = (const int*)  d_in[2];
    const float* Wih   = (const float*)d_in[3];
    const float* Whh   = (const float*)d_in[4];
    const float* bih   = (const float*)d_in[5];
    const float* bhh   = (const float*)d_in[6];
    const float* Whead = (const float*)d_in[7];
    const float* bhead = (const float*)d_in[8];
    float* out = (float*)d_out;

    const int B = in_sizes[0] / 3;          // 16384
    const int nblk = B / MELEM;             // 1024 blocks x 256 threads = 4 blocks/CU

    hipLaunchKernelGGL(gru_mfma_kernel, dim3(nblk), dim3(256), 0, stream,
                       z0, dtp, steps, Wih, Whh, bih, bhh, Whead, bhead, out);
}

// Round 10
// 4957.772 us; speedup vs baseline: 1.2836x; 1.2836x over previous
//
#include <hip/hip_runtime.h>

typedef _Float16 f16x8 __attribute__((ext_vector_type(8)));
typedef float f32x4 __attribute__((ext_vector_type(4)));

#define LOG2E 1.44269504088896340736f
#define HS 72             // f16 stride of h LDS rows
#define INV2K 4.8828125e-4f   // 2^-11
#define SC2K  2048.0f         // 2^11

__device__ __forceinline__ float fast_sigmoid(float x) {
    float t = __builtin_amdgcn_exp2f(-x * LOG2E);
    return __builtin_amdgcn_rcpf(1.f + t);
}
__device__ __forceinline__ float fast_tanh(float x) {
    float t = __builtin_amdgcn_exp2f(x * (2.f * LOG2E));
    return 1.f - 2.f * __builtin_amdgcn_rcpf(1.f + t);
}
__device__ __forceinline__ float bpermf(int sa, float v) {
    return __builtin_bit_cast(float,
        __builtin_amdgcn_ds_bpermute(sa, __builtin_bit_cast(int, v)));
}

// Wave-autonomous GRU: each wave owns 16 batch elems and ALL 64 hidden units.
// No cross-wave data flow -> ZERO barriers. 1 wave/SIMD, 512-VGPR budget.
__global__ __launch_bounds__(256, 1)
void gru_mfma_kernel(const float* __restrict__ z0,
                     const float* __restrict__ dtp,
                     const int* __restrict__ stepsp,
                     const float* __restrict__ Wih,
                     const float* __restrict__ Whh,
                     const float* __restrict__ bih,
                     const float* __restrict__ bhh,
                     const float* __restrict__ Whead,
                     const float* __restrict__ bhead,
                     float* __restrict__ out)
{
    // per-wave private h buffer, fp16 2-way split: [wave][part][elem*HS + unit]
    __shared__ _Float16 hls[4][2][16*HS];   // 18432 B

    const int tid = threadIdx.x;
    const int w   = tid >> 6;       // wave id: owns elems [blk*64+16w, +16)
    const int l   = tid & 63;
    const int c16 = l & 15;
    const int g   = l >> 4;         // 0..3

    const float dtv = dtp[0];
    const int nsteps = stepsp[0];
    const size_t T3 = (size_t)(nsteps + 1) * 3;
    const long blk = blockIdx.x;
    const int base_e = (int)blk*64 + w*16;

    // ---- B-fragments of W_hh for ALL 4 N-tiles (output units 16nt+c16) ----
    f16x8 WBh[3][2][4], WBl[3][2][4];   // [gate][kk][nt]
    #pragma unroll
    for (int gate = 0; gate < 3; ++gate)
        #pragma unroll
        for (int nt = 0; nt < 4; ++nt) {
            const float* row = Whh + (size_t)(gate*64 + 16*nt + c16) * 64;
            #pragma unroll
            for (int kk = 0; kk < 2; ++kk) {
                const float* p = row + 32*kk + 8*g;
                f16x8 bh_, bl_;
                #pragma unroll
                for (int j = 0; j < 8; ++j) {
                    float x = p[j];
                    _Float16 hi = (_Float16)x;
                    bh_[j] = hi;
                    bl_[j] = (_Float16)((x - (float)hi) * SC2K);
                }
                WBh[gate][kk][nt] = bh_;
                WBl[gate][kk][nt] = bl_;
            }
        }
    // ---- head B-fragments (cols 0..2 live in nt=0 tile) ----
    f16x8 HBh[2], HBl[2];
    {
        f16x8 zf = {0,0,0,0,0,0,0,0};
        HBh[0]=zf; HBh[1]=zf; HBl[0]=zf; HBl[1]=zf;
        if (c16 < 3) {
            #pragma unroll
            for (int kk = 0; kk < 2; ++kk) {
                const float* p = Whead + (size_t)c16*64 + 32*kk + 8*g;
                f16x8 bh_, bl_;
                #pragma unroll
                for (int j = 0; j < 8; ++j) {
                    float x = p[j];
                    _Float16 hi = (_Float16)x;
                    bh_[j] = hi;
                    bl_[j] = (_Float16)((x - (float)hi) * SC2K);
                }
                HBh[kk] = bh_; HBl[kk] = bl_;
            }
        }
    }

    // ---- per-lane scalars for each N-tile's unit (16nt + c16) ----
    float wir[4][3], wiu[4][3], win[4][3], brv[4], buv[4], binv[4], bhnv[4];
    #pragma unroll
    for (int nt = 0; nt < 4; ++nt) {
        const int unit = 16*nt + c16;
        #pragma unroll
        for (int j = 0; j < 3; ++j) {
            wir[nt][j] = Wih[(0*64+unit)*3+j];
            wiu[nt][j] = Wih[(1*64+unit)*3+j];
            win[nt][j] = Wih[(2*64+unit)*3+j];
        }
        brv[nt]  = bih[0*64+unit] + bhh[0*64+unit];
        buv[nt]  = bih[1*64+unit] + bhh[1*64+unit];
        binv[nt] = bih[2*64+unit];
        bhnv[nt] = bhh[2*64+unit];
    }
    float bhc = 0.f;
    if (c16 < 3) bhc = bhead[c16];

    // ---- z in registers: lane holds rows 4g+r of this wave's 16-elem tile ----
    float zreg[4][3];
    #pragma unroll
    for (int r = 0; r < 4; ++r)
        #pragma unroll
        for (int c = 0; c < 3; ++c)
            zreg[r][c] = z0[(size_t)(base_e + 4*g + r)*3 + c];

    // ---- out cursor (lanes c16<3 of EVERY wave store their own elems) ----
    float* o0 = out;
    if (c16 < 3)
        o0 = out + (size_t)(base_e + 4*g)*T3 + c16;
    #pragma unroll
    for (int c = 0; c < 3; ++c)
        if (c16 == c) {
            #pragma unroll
            for (int r = 0; r < 4; ++r) o0[(size_t)r*T3] = zreg[r][c];
        }
    o0 += 3;   // -> t=1

    // hoisted bpermute byte-addresses
    const int sa0 = (l & 48) << 2;
    const int sa1 = sa0 + 4;
    const int sa2 = sa0 + 8;

    // step-invariant LDS element offset for A-fragments (row = c16)
    const int adA0 = c16*HS + 8*g;

    // ---- zero this wave's h buffer (h_0 = 0); wave-private, in-order ----
    {
        uint* hz = (uint*)&hls[w][0][0];
        #pragma unroll
        for (int k = 0; k < (2*16*HS)/(2*64); ++k) hz[l + 64*k] = 0u;
    }

    float hC[4][4] = {{0,0,0,0},{0,0,0,0},{0,0,0,0},{0,0,0,0}};   // [nt][r]

#define STEP(DOZ) do {                                                           \
    f16x8 FAh0 = *(const f16x8*)&hls[w][0][adA0];                                \
    f16x8 FAh1 = *(const f16x8*)&hls[w][0][adA0 + 32];                           \
    f16x8 FAl0 = *(const f16x8*)&hls[w][1][adA0];                                \
    f16x8 FAl1 = *(const f16x8*)&hls[w][1][adA0 + 32];                           \
    if (DOZ) {                                                                   \
        f32x4 ha = {0.f,0.f,0.f,0.f}, hb = {0.f,0.f,0.f,0.f};                    \
        ha = __builtin_amdgcn_mfma_f32_16x16x32_f16(FAh0, HBh[0], ha, 0,0,0);    \
        ha = __builtin_amdgcn_mfma_f32_16x16x32_f16(FAh1, HBh[1], ha, 0,0,0);    \
        hb = __builtin_amdgcn_mfma_f32_16x16x32_f16(FAh0, HBl[0], hb, 0,0,0);    \
        hb = __builtin_amdgcn_mfma_f32_16x16x32_f16(FAl0, HBh[0], hb, 0,0,0);    \
        hb = __builtin_amdgcn_mfma_f32_16x16x32_f16(FAh1, HBl[1], hb, 0,0,0);    \
        hb = __builtin_amdgcn_mfma_f32_16x16x32_f16(FAl1, HBh[1], hb, 0,0,0);    \
        _Pragma("unroll")                                                        \
        for (int r = 0; r < 4; ++r) {                                            \
            float fv = ha[r] + INV2K*hb[r] + bhc;                                \
            zreg[r][0] = __builtin_fmaf(dtv, bpermf(sa0, fv), zreg[r][0]);       \
            zreg[r][1] = __builtin_fmaf(dtv, bpermf(sa1, fv), zreg[r][1]);       \
            zreg[r][2] = __builtin_fmaf(dtv, bpermf(sa2, fv), zreg[r][2]);       \
        }                                                                        \
        _Pragma("unroll")                                                        \
        for (int c = 0; c < 3; ++c)                                              \
            if (c16 == c) {                                                      \
                _Pragma("unroll")                                                \
                for (int r = 0; r < 4; ++r) o0[(size_t)r*T3] = zreg[r][c];       \
            }                                                                    \
        o0 += 3;                                                                 \
    }                                                                            \
    _Pragma("unroll")                                                            \
    for (int nt = 0; nt < 4; ++nt) {                                             \
        f32x4 a1r={0.f,0.f,0.f,0.f}, a2r={0.f,0.f,0.f,0.f};                      \
        f32x4 a1u={0.f,0.f,0.f,0.f}, a2u={0.f,0.f,0.f,0.f};                      \
        f32x4 a1n={0.f,0.f,0.f,0.f}, a2n={0.f,0.f,0.f,0.f};                      \
        a1r = __builtin_amdgcn_mfma_f32_16x16x32_f16(FAh0, WBh[0][0][nt], a1r, 0,0,0); \
        a2r = __builtin_amdgcn_mfma_f32_16x16x32_f16(FAh0, WBl[0][0][nt], a2r, 0,0,0); \
        a2r = __builtin_amdgcn_mfma_f32_16x16x32_f16(FAl0, WBh[0][0][nt], a2r, 0,0,0); \
        a1r = __builtin_amdgcn_mfma_f32_16x16x32_f16(FAh1, WBh[0][1][nt], a1r, 0,0,0); \
        a2r = __builtin_amdgcn_mfma_f32_16x16x32_f16(FAh1, WBl[0][1][nt], a2r, 0,0,0); \
        a2r = __builtin_amdgcn_mfma_f32_16x16x32_f16(FAl1, WBh[0][1][nt], a2r, 0,0,0); \
        a1u = __builtin_amdgcn_mfma_f32_16x16x32_f16(FAh0, WBh[1][0][nt], a1u, 0,0,0); \
        a2u = __builtin_amdgcn_mfma_f32_16x16x32_f16(FAh0, WBl[1][0][nt], a2u, 0,0,0); \
        a2u = __builtin_amdgcn_mfma_f32_16x16x32_f16(FAl0, WBh[1][0][nt], a2u, 0,0,0); \
        a1u = __builtin_amdgcn_mfma_f32_16x16x32_f16(FAh1, WBh[1][1][nt], a1u, 0,0,0); \
        a2u = __builtin_amdgcn_mfma_f32_16x16x32_f16(FAh1, WBl[1][1][nt], a2u, 0,0,0); \
        a2u = __builtin_amdgcn_mfma_f32_16x16x32_f16(FAl1, WBh[1][1][nt], a2u, 0,0,0); \
        a1n = __builtin_amdgcn_mfma_f32_16x16x32_f16(FAh0, WBh[2][0][nt], a1n, 0,0,0); \
        a2n = __builtin_amdgcn_mfma_f32_16x16x32_f16(FAh0, WBl[2][0][nt], a2n, 0,0,0); \
        a2n = __builtin_amdgcn_mfma_f32_16x16x32_f16(FAl0, WBh[2][0][nt], a2n, 0,0,0); \
        a1n = __builtin_amdgcn_mfma_f32_16x16x32_f16(FAh1, WBh[2][1][nt], a1n, 0,0,0); \
        a2n = __builtin_amdgcn_mfma_f32_16x16x32_f16(FAh1, WBl[2][1][nt], a2n, 0,0,0); \
        a2n = __builtin_amdgcn_mfma_f32_16x16x32_f16(FAl1, WBh[2][1][nt], a2n, 0,0,0); \
        _Pragma("unroll")                                                        \
        for (int r = 0; r < 4; ++r) {                                            \
            float z0v = zreg[r][0], z1v = zreg[r][1], z2v = zreg[r][2];          \
            float ar  = a1r[r] + INV2K*a2r[r] + brv[nt]                          \
                      + (wir[nt][0]*z0v + wir[nt][1]*z1v + wir[nt][2]*z2v);      \
            float au  = a1u[r] + INV2K*a2u[r] + buv[nt]                          \
                      + (wiu[nt][0]*z0v + wiu[nt][1]*z1v + wiu[nt][2]*z2v);      \
            float anh = a1n[r] + INV2K*a2n[r] + bhnv[nt];                        \
            float ain = binv[nt]                                                 \
                      + (win[nt][0]*z0v + win[nt][1]*z1v + win[nt][2]*z2v);      \
            float rg = fast_sigmoid(ar);                                         \
            float ug = fast_sigmoid(au);                                         \
            float ng = fast_tanh(ain + rg*anh);                                  \
            float hn = ng + ug*(hC[nt][r] - ng);                                 \
            hC[nt][r] = hn;                                                      \
            _Float16 hi = (_Float16)hn;                                          \
            _Float16 lo = (_Float16)((hn - (float)hi) * SC2K);                   \
            hls[w][0][(4*g+r)*HS + 16*nt + c16] = hi;                            \
            hls[w][1][(4*g+r)*HS + 16*nt + c16] = lo;                            \
        }                                                                        \
    }                                                                            \
} while (0)

    // ---- main loop: NO barriers anywhere (wave-private LDS, in-order DS) ----
    STEP(false);
    #pragma unroll 1
    for (int t = 1; t < nsteps; ++t) STEP(true);

    // ---- epilogue: z(nsteps) from head over h(nsteps) ----
    {
        f16x8 FAh0 = *(const f16x8*)&hls[w][0][adA0];
        f16x8 FAh1 = *(const f16x8*)&hls[w][0][adA0 + 32];
        f16x8 FAl0 = *(const f16x8*)&hls[w][1][adA0];
        f16x8 FAl1 = *(const f16x8*)&hls[w][1][adA0 + 32];
        f32x4 ha = {0.f,0.f,0.f,0.f}, hb = {0.f,0.f,0.f,0.f};
        ha = __builtin_amdgcn_mfma_f32_16x16x32_f16(FAh0, HBh[0], ha, 0,0,0);
        ha = __builtin_amdgcn_mfma_f32_16x16x32_f16(FAh1, HBh[1], ha, 0,0,0);
        hb = __builtin_amdgcn_mfma_f32_16x16x32_f16(FAh0, HBl[0], hb, 0,0,0);
        hb = __builtin_amdgcn_mfma_f32_16x16x32_f16(FAl0, HBh[0], hb, 0,0,0);
        hb = __builtin_amdgcn_mfma_f32_16x16x32_f16(FAh1, HBl[1], hb, 0,0,0);
        hb = __builtin_amdgcn_mfma_f32_16x16x32_f16(FAl1, HBh[1], hb, 0,0,0);
        #pragma unroll
        for (int r = 0; r < 4; ++r) {
            float fv = ha[r] + INV2K*hb[r] + bhc;
            zreg[r][0] = __builtin_fmaf(dtv, bpermf(sa0, fv), zreg[r][0]);
            zreg[r][1] = __builtin_fmaf(dtv, bpermf(sa1, fv), zreg[r][1]);
            zreg[r][2] = __builtin_fmaf(dtv, bpermf(sa2, fv), zreg[r][2]);
        }
        #pragma unroll
        for (int c = 0; c < 3; ++c)
            if (c16 == c) {
                #pragma unroll
                for (int r = 0; r < 4; ++r) o0[(size_t)r*T3] = zreg[r][c];
            }
    }
#undef STEP
}

extern "C" void kernel_launch(void* const* d_in, const int* in_sizes, int n_in,
                              void* d_out, int out_size, void* d_ws, size_t ws_size,
                              hipStream_t stream) {
    const float* z0    = (const float*)d_in[0];
    const float* dtp   = (const float*)d_in[1];
    const int*   steps = (const int*)  d_in[2];
    const float* Wih   = (const float*)d_in[3];
    const float* Whh   = (const float*)d_in[4];
    const float* bih   = (const float*)d_in[5];
    const float* bhh   = (const float*)d_in[6];
    const float* Whead = (const float*)d_in[7];
    const float* bhead = (const float*)d_in[8];
    float* out = (float*)d_out;

    const int B = in_sizes[0] / 3;          // 16384
    const int nblk = B / 64;                // 256 blocks x 4 waves = 1 wave/SIMD

    hipLaunchKernelGGL(gru_mfma_kernel, dim3(nblk), dim3(256), 0, stream,
                       z0, dtp, steps, Wih, Whh, bih, bhh, Whead, bhead, out);
}